// Round 5
// baseline (832.519 us; speedup 1.0000x reference)
//
#include <hip/hip_runtime.h>

#define NNODES 100000
#define NEDGES 1600000
#define HDIM 64
#define NPART 8
#define PRANGE 12500        // NNODES / NPART
#define NPB 25              // nodes per bucket
#define NBUCKET 4000        // NNODES / NPB
#define BCAP 576            // bucket capacity: mean 400 + 8.8 sigma

// ---------- bf16x2 pack/unpack (RNE pack; exact unpack) ----------
__device__ inline unsigned pack_bf16x2(float a, float b) {
    union { float f; unsigned u; } ua, ub;
    ua.f = a; ub.f = b;
    unsigned ra = (ua.u + 0x7FFFu + ((ua.u >> 16) & 1u)) >> 16;
    unsigned rb = (ub.u + 0x7FFFu + ((ub.u >> 16) & 1u)) >> 16;
    return ra | (rb << 16);
}
__device__ inline float2 unpack_bf16x2(unsigned p) {
    union { unsigned u; float f; } a, b;
    a.u = p << 16;
    b.u = p & 0xFFFF0000u;
    return make_float2(a.f, b.f);
}

// ---------------- init bucket cursors to region bases ----------------
__global__ void bkcur_init(int* bkcur_d, int* bkcur_s) {
    int i = blockIdx.x * blockDim.x + threadIdx.x;
    if (i < NBUCKET) { bkcur_d[i] = i * BCAP; bkcur_s[i] = i * BCAP; }
}

// ---------------- in-degree count (XCD-partitioned) ----------------
__global__ void deg_part(const int* __restrict__ dst, int* cnt_d, int ne) {
    int part = blockIdx.x & (NPART - 1);
    int blk = blockIdx.x >> 3, nblk = gridDim.x >> 3;
    int lo = part * PRANGE;
    for (int i = blk * blockDim.x + threadIdx.x; i < ne; i += nblk * blockDim.x) {
        int d = dst[i];
        if ((unsigned)(d - lo) < PRANGE) atomicAdd(&cnt_d[d], 1);
    }
}

__global__ void make_dinv(const int* __restrict__ cnt_d, float* dinv, int n) {
    int i = blockIdx.x * blockDim.x + threadIdx.x;
    if (i < n) dinv[i] = rsqrtf((float)(cnt_d[i] + 1));   // +1 self-loop
}

// ---------------- pass A: bucketize edges (XCD-partitioned, sequential writes) ----
// dst-stream entry (4B): (d_local<<17) | s ;  src-stream entry (8B): ((s_local<<17)|d, adjv)
__global__ void passA(const int* __restrict__ src, const int* __restrict__ dst,
                      const float* __restrict__ adjv,
                      int* bkcur_d, int* bkcur_s,
                      unsigned* __restrict__ stream_d, int2* __restrict__ stream_s, int ne) {
    int part = blockIdx.x & (NPART - 1);
    int blk = blockIdx.x >> 3, nblk = gridDim.x >> 3;
    int lo = part * PRANGE;
    for (int i = blk * blockDim.x + threadIdx.x; i < ne; i += nblk * blockDim.x) {
        int s = src[i], d = dst[i];
        if ((unsigned)(d - lo) < PRANGE) {
            int bd = d / NPB;
            int p = atomicAdd(&bkcur_d[bd], 1);
            stream_d[p] = ((unsigned)(d - bd * NPB) << 17) | (unsigned)s;
        }
        if ((unsigned)(s - lo) < PRANGE) {
            int bs = s / NPB;
            int q = atomicAdd(&bkcur_s[bs], 1);
            stream_s[q] = make_int2((int)(((unsigned)(s - bs * NPB) << 17) | (unsigned)d),
                                    __float_as_int(adjv[i]));
        }
    }
}

// ---------------- bucket-count exclusive scan (single block) ----------------
__global__ void bucket_scan(const int* __restrict__ bkcur_d, const int* __restrict__ bkcur_s,
                            int* bkbase_d, int* bkbase_s, int* rp_d, int* rp_s) {
    __shared__ int L[4096];
    int tid = threadIdx.x;
    for (int rep = 0; rep < 2; ++rep) {
        const int* cur = rep ? bkcur_s : bkcur_d;
        int* base = rep ? bkbase_s : bkbase_d;
        for (int i = tid; i < 4096; i += 1024)
            L[i] = (i < NBUCKET) ? (cur[i] - i * BCAP) : 0;
        __syncthreads();
        for (int off = 1; off < 4096; off <<= 1) {
            int t[4];
#pragma unroll
            for (int k = 0; k < 4; ++k) {
                int idx = tid + k * 1024;
                t[k] = L[idx] + ((idx >= off) ? L[idx - off] : 0);
            }
            __syncthreads();
#pragma unroll
            for (int k = 0; k < 4; ++k) L[tid + k * 1024] = t[k];
            __syncthreads();
        }
        for (int i = tid; i < NBUCKET; i += 1024)
            base[i] = i ? L[i - 1] : 0;          // exclusive
        __syncthreads();
    }
    if (tid == 0) { rp_d[NNODES] = NEDGES; rp_s[NNODES] = NEDGES; }
}

// ---------------- pass B: per-bucket place entries into final CSR ----------------
// also emits rp_d / rp_s slices for this bucket's node range
__global__ void passB(const unsigned* __restrict__ stream_d, const int2* __restrict__ stream_s,
                      const int* __restrict__ bkcur_d, const int* __restrict__ bkcur_s,
                      const int* __restrict__ bkbase_d, const int* __restrict__ bkbase_s,
                      const float* __restrict__ dinv,
                      int2* __restrict__ csr_d, int2* __restrict__ csr_s,
                      int* rp_d, int* rp_s) {
    int b = blockIdx.x;
    int tid = threadIdx.x;
    __shared__ int lh_d[NPB], lb_d[NPB], lc_d[NPB];
    __shared__ int lh_s[NPB], lb_s[NPB], lc_s[NPB];
    int cntd = bkcur_d[b] - b * BCAP;
    int cnts = bkcur_s[b] - b * BCAP;
    int based = bkbase_d[b], bases = bkbase_s[b];
    if (tid < NPB) { lh_d[tid] = 0; lh_s[tid] = 0; }
    __syncthreads();
    for (int j = tid; j < cntd; j += 256) atomicAdd(&lh_d[stream_d[b * BCAP + j] >> 17], 1);
    for (int j = tid; j < cnts; j += 256) atomicAdd(&lh_s[((unsigned)stream_s[b * BCAP + j].x) >> 17], 1);
    __syncthreads();
    if (tid == 0)  { int a = 0; for (int i = 0; i < NPB; ++i) { lb_d[i] = a; a += lh_d[i]; } }
    if (tid == 64) { int a = 0; for (int i = 0; i < NPB; ++i) { lb_s[i] = a; a += lh_s[i]; } }
    __syncthreads();
    if (tid < NPB) {
        lc_d[tid] = lb_d[tid];
        lc_s[tid] = lb_s[tid];
        rp_d[b * NPB + tid] = based + lb_d[tid];
        rp_s[b * NPB + tid] = bases + lb_s[tid];
    }
    __syncthreads();
    for (int j = tid; j < cntd; j += 256) {
        unsigned e = stream_d[b * BCAP + j];
        int s = e & 0x1FFFF;
        int dl = e >> 17;
        int p = atomicAdd(&lc_d[dl], 1);
        csr_d[based + p] = make_int2(s, __float_as_int(dinv[s]));
    }
    for (int j = tid; j < cnts; j += 256) {
        int2 e = stream_s[b * BCAP + j];
        int d = e.x & 0x1FFFF;
        int sl = ((unsigned)e.x) >> 17;
        int p = atomicAdd(&lc_s[sl], 1);
        csr_s[bases + p] = make_int2(d, e.y);
    }
}

// ---------------- GEMM [n,64]@[64,64] -> f32 out (+bias, optional relu) ----------------
__global__ void gemm64(const float* __restrict__ X, const float* __restrict__ W,
                       const float* __restrict__ bias, float* __restrict__ Y,
                       int n, int do_relu) {
    __shared__ float Ws[HDIM * HDIM];
    __shared__ float xs[4][HDIM];
    int tid = threadIdx.x;
    for (int i = tid; i < HDIM * HDIM; i += 256) Ws[i] = W[i];
    int c = tid & 63;
    int rl = tid >> 6;
    float bc = bias ? bias[c] : 0.0f;
    __syncthreads();
    for (int r0 = blockIdx.x * 4; r0 < n; r0 += gridDim.x * 4) {
        int r = r0 + rl;
        if (r < n) {
            xs[rl][c] = X[r * HDIM + c];
            float acc = bc;
#pragma unroll
            for (int k = 0; k < HDIM; ++k) acc += xs[rl][k] * Ws[k * HDIM + c];
            Y[r * HDIM + c] = do_relu ? fmaxf(acc, 0.0f) : acc;
        }
    }
}

// ---------------- GEMM [n,64]@[64,64] -> packed bf16x2 out ----------------
__global__ void gemm64p(const float* __restrict__ X, const float* __restrict__ W,
                        unsigned* __restrict__ Yp, int n) {
    __shared__ float Ws[HDIM * HDIM];
    __shared__ float xs[8][HDIM];
    int tid = threadIdx.x;
    for (int i = tid; i < HDIM * HDIM; i += 256) Ws[i] = W[i];
    int pr = tid & 31;
    int rl = tid >> 5;
    __syncthreads();
    const float2* X2 = (const float2*)X;
    for (int r0 = blockIdx.x * 8; r0 < n; r0 += gridDim.x * 8) {
        int r = r0 + rl;
        if (r < n) {
            float2 xv = X2[(size_t)r * 32 + pr];
            xs[rl][2 * pr] = xv.x;
            xs[rl][2 * pr + 1] = xv.y;
            float acc0 = 0.0f, acc1 = 0.0f;
#pragma unroll
            for (int k = 0; k < HDIM; ++k) {
                float xk = xs[rl][k];
                acc0 += xk * Ws[k * HDIM + 2 * pr];
                acc1 += xk * Ws[k * HDIM + 2 * pr + 1];
            }
            Yp[(size_t)r * 32 + pr] = pack_bf16x2(acc0, acc1);
        }
    }
}

// ---------------- fused GCN gather + bias + LN + ReLU ----------------
__global__ void conv_ln(const unsigned* __restrict__ xwp, const int* __restrict__ rp,
                        const int2* __restrict__ csr, const float* __restrict__ dinv,
                        const float* __restrict__ cb, const float* __restrict__ g,
                        const float* __restrict__ b, float* __restrict__ h, int n) {
    int gid = blockIdx.x * blockDim.x + threadIdx.x;
    int node = gid >> 5;
    if (node >= n) return;
    int c2 = gid & 31;                       // channel pair
    int wl = threadIdx.x & 63;               // lane in wave
    int hb = wl & 32;                        // half base (0 or 32)
    int e0 = rp[node], e1 = rp[node + 1];
    float di = dinv[node];
    float2 self = unpack_bf16x2(xwp[(size_t)node * 32 + c2]);
    float acc0 = self.x * di, acc1 = self.y * di;
    for (int j0 = e0; j0 < e1; j0 += 32) {
        int jj = j0 + c2;
        int sidx = 0; float dv = 0.0f;
        if (jj < e1) { int2 pl = csr[jj]; sidx = pl.x; dv = __int_as_float(pl.y); }
        int cnt = min(32, e1 - j0);
        for (int k = 0; k < cnt; ++k) {
            int sv = __shfl(sidx, hb | k);
            float dvk = __shfl(dv, hb | k);
            float2 xv = unpack_bf16x2(xwp[(size_t)sv * 32 + c2]);
            acc0 += xv.x * dvk;
            acc1 += xv.y * dvk;
        }
    }
    float v0 = acc0 * di + cb[2 * c2];
    float v1 = acc1 * di + cb[2 * c2 + 1];
    float s = v0 + v1;
#pragma unroll
    for (int off = 16; off; off >>= 1) s += __shfl_xor(s, off);
    float mu = s * (1.0f / 64.0f);
    float d0 = v0 - mu, d1 = v1 - mu;
    float q = d0 * d0 + d1 * d1;
#pragma unroll
    for (int off = 16; off; off >>= 1) q += __shfl_xor(q, off);
    float r = rsqrtf(q * (1.0f / 64.0f) + 1e-5f);
    float o0 = fmaxf(d0 * r * g[2 * c2] + b[2 * c2], 0.0f);
    float o1 = fmaxf(d1 * r * g[2 * c2 + 1] + b[2 * c2 + 1], 0.0f);
    *(float2*)&h[(size_t)node * HDIM + 2 * c2] = make_float2(o0, o1);
}

// ---------------- residual gather: res[s] = sum adj * xw[dst] ----------------
__global__ void res_gather(const unsigned* __restrict__ xwp, const int* __restrict__ rp,
                           const int2* __restrict__ csr, float* __restrict__ res, int n) {
    int gid = blockIdx.x * blockDim.x + threadIdx.x;
    int node = gid >> 5;
    if (node >= n) return;
    int c2 = gid & 31;
    int wl = threadIdx.x & 63;
    int hb = wl & 32;
    int e0 = rp[node], e1 = rp[node + 1];
    float acc0 = 0.0f, acc1 = 0.0f;
    for (int j0 = e0; j0 < e1; j0 += 32) {
        int jj = j0 + c2;
        int didx = 0; float vv = 0.0f;
        if (jj < e1) { int2 pl = csr[jj]; didx = pl.x; vv = __int_as_float(pl.y); }
        int cnt = min(32, e1 - j0);
        for (int k = 0; k < cnt; ++k) {
            int dv = __shfl(didx, hb | k);
            float vk = __shfl(vv, hb | k);
            float2 xv = unpack_bf16x2(xwp[(size_t)dv * 32 + c2]);
            acc0 += vk * xv.x;
            acc1 += vk * xv.y;
        }
    }
    *(float2*)&res[(size_t)node * HDIM + 2 * c2] = make_float2(acc0, acc1);
}

extern "C" void kernel_launch(void* const* d_in, const int* in_sizes, int n_in,
                              void* d_out, int out_size, void* d_ws, size_t ws_size,
                              hipStream_t stream) {
    const float* x     = (const float*)d_in[0];
    const float* xorg  = (const float*)d_in[1];
    const float* adjv  = (const float*)d_in[2];
    const float* Wi    = (const float*)d_in[3];
    const float* bi    = (const float*)d_in[4];
    const float* convW = (const float*)d_in[5];
    const float* convB = (const float*)d_in[6];
    const float* lng   = (const float*)d_in[7];
    const float* lnb   = (const float*)d_in[8];
    const float* Wl    = (const float*)d_in[9];
    const float* bl    = (const float*)d_in[10];
    const float* Wres  = (const float*)d_in[11];
    const int*   ei    = (const int*)d_in[12];
    const int* src = ei;
    const int* dst = ei + NEDGES;

    float* out = (float*)d_out;               // [N,64]
    float* res = out + (size_t)NNODES * HDIM; // [N,64]

    // ---- workspace layout ----
    float* h      = (float*)d_ws;                           // N*64 f32
    unsigned* xwp = (unsigned*)(h + (size_t)NNODES * HDIM); // N*32 u32
    float* dinv   = (float*)(xwp + (size_t)NNODES * 32);    // N
    int* cnt_d    = (int*)(dinv + NNODES);                  // N
    int* rp_d     = cnt_d + NNODES;                         // N+1
    int* rp_s     = rp_d + (NNODES + 1);                    // N+1
    int* bkcur_d  = rp_s + (NNODES + 1);                    // NBUCKET
    int* bkcur_s  = bkcur_d + NBUCKET;                      // NBUCKET
    int* bkbase_d = bkcur_s + NBUCKET;                      // NBUCKET
    int* bkbase_s = bkbase_d + NBUCKET;                     // NBUCKET
    size_t ofs = (size_t)(bkbase_s + NBUCKET - (int*)d_ws);
    ofs = (ofs + 1) & ~(size_t)1;
    int2* csr_d = (int2*)((int*)d_ws + ofs);                // E int2
    int2* csr_s = csr_d + NEDGES;                           // E int2
    // stream buffers overlay h/xwp (dead until GEMMs; pass B completes first)
    unsigned* stream_d = (unsigned*)d_ws;                   // NBUCKET*BCAP u32  (9.2 MB)
    int2* stream_s = (int2*)(stream_d + (size_t)NBUCKET * BCAP); // NBUCKET*BCAP int2 (18.4 MB)

    const int ngrid1 = (NNODES + 255) / 256;
    const int ngrid32 = (NNODES * 32 + 255) / 256;

    // ---- CSR build (bucketed two-pass counting sort) ----
    hipMemsetAsync(cnt_d, 0, (size_t)NNODES * sizeof(int), stream);
    bkcur_init<<<(NBUCKET + 255) / 256, 256, 0, stream>>>(bkcur_d, bkcur_s);
    deg_part<<<2048, 256, 0, stream>>>(dst, cnt_d, NEDGES);
    make_dinv<<<ngrid1, 256, 0, stream>>>(cnt_d, dinv, NNODES);
    passA<<<2048, 256, 0, stream>>>(src, dst, adjv, bkcur_d, bkcur_s,
                                    stream_d, stream_s, NEDGES);
    bucket_scan<<<1, 1024, 0, stream>>>(bkcur_d, bkcur_s, bkbase_d, bkbase_s, rp_d, rp_s);
    passB<<<NBUCKET, 256, 0, stream>>>(stream_d, stream_s, bkcur_d, bkcur_s,
                                       bkbase_d, bkbase_s, dinv, csr_d, csr_s, rp_d, rp_s);

    // ---- h0 = relu(x @ Wi + bi) ----
    gemm64<<<2048, 256, 0, stream>>>(x, Wi, bi, h, NNODES, 1);

    // ---- residual = gather_src(adj * (x_org @ Wres)[dst]) ----
    gemm64p<<<2048, 256, 0, stream>>>(xorg, Wres, xwp, NNODES);
    res_gather<<<ngrid32, 256, 0, stream>>>(xwp, rp_s, csr_s, res, NNODES);

    // ---- 3 GCN layers: packed gemm -> fused gather+LN+ReLU ----
    for (int l = 0; l < 3; ++l) {
        gemm64p<<<2048, 256, 0, stream>>>(h, convW + l * HDIM * HDIM, xwp, NNODES);
        conv_ln<<<ngrid32, 256, 0, stream>>>(xwp, rp_d, csr_d, dinv,
                                             convB + l * HDIM, lng + l * HDIM,
                                             lnb + l * HDIM, h, NNODES);
    }

    // ---- out = h @ Wl + bl ----
    gemm64<<<2048, 256, 0, stream>>>(h, Wl, bl, out, NNODES, 0);
}

// Round 6
// 594.746 us; speedup vs baseline: 1.3998x; 1.3998x over previous
//
#include <hip/hip_runtime.h>

#define NNODES 100000
#define NEDGES 1600000
#define HDIM 64
#define SCAN_BS 512
#define NBLK_SCAN ((NNODES + SCAN_BS - 1) / SCAN_BS)   // 196
#define NPART 8
#define PRANGE 12500   // NNODES / NPART exactly

// ---------- bf16x2 pack/unpack (RNE pack; exact unpack) ----------
__device__ inline unsigned pack_bf16x2(float a, float b) {
    union { float f; unsigned u; } ua, ub;
    ua.f = a; ub.f = b;
    unsigned ra = (ua.u + 0x7FFFu + ((ua.u >> 16) & 1u)) >> 16;
    unsigned rb = (ub.u + 0x7FFFu + ((ub.u >> 16) & 1u)) >> 16;
    return ra | (rb << 16);
}
__device__ inline float2 unpack_bf16x2(unsigned p) {
    union { unsigned u; float f; } a, b;
    a.u = p << 16;
    b.u = p & 0xFFFF0000u;
    return make_float2(a.f, b.f);
}

// ---------------- CSR build: histogram (4 edges/thread) ----------------
__global__ void hist4(const int4* __restrict__ src4, const int4* __restrict__ dst4,
                      int* cnt_s, int* cnt_d, int ne4) {
    int i = blockIdx.x * blockDim.x + threadIdx.x;
    if (i >= ne4) return;
    int4 s = src4[i], d = dst4[i];
    atomicAdd(&cnt_s[s.x], 1); atomicAdd(&cnt_s[s.y], 1);
    atomicAdd(&cnt_s[s.z], 1); atomicAdd(&cnt_s[s.w], 1);
    atomicAdd(&cnt_d[d.x], 1); atomicAdd(&cnt_d[d.y], 1);
    atomicAdd(&cnt_d[d.z], 1); atomicAdd(&cnt_d[d.w], 1);
}

__global__ void make_dinv(const int* __restrict__ cnt_d, float* dinv, int n) {
    int i = blockIdx.x * blockDim.x + threadIdx.x;
    if (i < n) dinv[i] = rsqrtf((float)(cnt_d[i] + 1));   // +1 self-loop
}

// ---------------- CSR build: 2-level exclusive scan ----------------
__global__ void scan1(const int* __restrict__ cnt, int* rp, int* bsum, int n) {
    __shared__ int temp[SCAN_BS];
    int tid = threadIdx.x;
    int i = blockIdx.x * SCAN_BS + tid;
    int v = (i < n) ? cnt[i] : 0;
    temp[tid] = v;
    __syncthreads();
    for (int off = 1; off < SCAN_BS; off <<= 1) {
        int t = (tid >= off) ? temp[tid - off] : 0;
        __syncthreads();
        temp[tid] += t;
        __syncthreads();
    }
    int inc = temp[tid];
    if (i < n) rp[i] = inc - v;
    if (tid == SCAN_BS - 1) bsum[blockIdx.x] = inc;
}

__global__ void scan2(const int* __restrict__ bsum, int* boff, int nb) {
    __shared__ int temp[256];
    int tid = threadIdx.x;
    int v = (tid < nb) ? bsum[tid] : 0;
    temp[tid] = v;
    __syncthreads();
    for (int off = 1; off < 256; off <<= 1) {
        int t = (tid >= off) ? temp[tid - off] : 0;
        __syncthreads();
        temp[tid] += t;
        __syncthreads();
    }
    if (tid < nb) boff[tid] = temp[tid] - v;
}

__global__ void scan3(int* rp, int* cur, const int* __restrict__ boff, int n, int total) {
    int i = blockIdx.x * blockDim.x + threadIdx.x;
    if (i < n) {
        int v = rp[i] + boff[i / SCAN_BS];
        rp[i] = v;
        cur[i] = v;
    }
    if (i == 0) rp[n] = total;
}

// ---------------- CSR fill, XCD-partitioned scatter ----------------
// dst-CSR payload: (src, dinv[src]);  src-CSR payload: (dst, adjv)
__global__ void fill_csr_part(const int* __restrict__ src, const int* __restrict__ dst,
                              const float* __restrict__ adjv, const float* __restrict__ dinv,
                              int* cur_d, int* cur_s,
                              int2* __restrict__ csr_d, int2* __restrict__ csr_s, int ne) {
    int part = blockIdx.x & (NPART - 1);
    int blk  = blockIdx.x >> 3;
    int nblk = gridDim.x >> 3;
    int lo = part * PRANGE;
    for (int i = blk * blockDim.x + threadIdx.x; i < ne; i += nblk * blockDim.x) {
        int s = src[i], d = dst[i];
        if ((unsigned)(d - lo) < PRANGE) {
            int2 pd; pd.x = s; pd.y = __float_as_int(dinv[s]);
            int p = atomicAdd(&cur_d[d], 1);
            csr_d[p] = pd;
        }
        if ((unsigned)(s - lo) < PRANGE) {
            int2 ps; ps.x = d; ps.y = __float_as_int(adjv[i]);
            int q = atomicAdd(&cur_s[s], 1);
            csr_s[q] = ps;
        }
    }
}

// ---------------- GEMM [n,64]@[64,64] -> f32 (+bias, optional relu) ----------------
// 256 thr = 16 rows x 16 quad-cols; thread computes channels 4q..4q+3.
// W via ds_read_b128 (2-way conflict = free); xs stride 68 (pad) -> conflict-free broadcast.
__global__ void gemm64(const float* __restrict__ X, const float* __restrict__ W,
                       const float* __restrict__ bias, float* __restrict__ Y,
                       int n, int do_relu) {
    __shared__ float Ws[HDIM * HDIM];
    __shared__ float xs[16][68];
    int tid = threadIdx.x;
    for (int i = tid; i < HDIM * HDIM; i += 256) Ws[i] = W[i];
    int q = tid & 15;
    int rl = tid >> 4;
    float4 bc = bias ? *(const float4*)&bias[4 * q] : make_float4(0.f, 0.f, 0.f, 0.f);
    __syncthreads();
    for (int r0 = blockIdx.x * 16; r0 < n; r0 += gridDim.x * 16) {
        int r = r0 + rl;
        if (r < n) {
            // row load: 16 threads (same wave) x float4 = full row; same-wave LDS R/W, no barrier
            *(float4*)&xs[rl][4 * q] = *(const float4*)&X[(size_t)r * HDIM + 4 * q];
            float4 acc = bc;
#pragma unroll
            for (int k = 0; k < HDIM; ++k) {
                float xk = xs[rl][k];
                float4 w4 = *(const float4*)&Ws[k * HDIM + 4 * q];
                acc.x += xk * w4.x; acc.y += xk * w4.y;
                acc.z += xk * w4.z; acc.w += xk * w4.w;
            }
            if (do_relu) {
                acc.x = fmaxf(acc.x, 0.f); acc.y = fmaxf(acc.y, 0.f);
                acc.z = fmaxf(acc.z, 0.f); acc.w = fmaxf(acc.w, 0.f);
            }
            *(float4*)&Y[(size_t)r * HDIM + 4 * q] = acc;
        }
    }
}

// ---------------- GEMM [n,64]@[64,64] -> packed bf16x2 out ----------------
__global__ void gemm64p(const float* __restrict__ X, const float* __restrict__ W,
                        unsigned* __restrict__ Yp, int n) {
    __shared__ float Ws[HDIM * HDIM];
    __shared__ float xs[16][68];
    int tid = threadIdx.x;
    for (int i = tid; i < HDIM * HDIM; i += 256) Ws[i] = W[i];
    int q = tid & 15;
    int rl = tid >> 4;
    __syncthreads();
    for (int r0 = blockIdx.x * 16; r0 < n; r0 += gridDim.x * 16) {
        int r = r0 + rl;
        if (r < n) {
            *(float4*)&xs[rl][4 * q] = *(const float4*)&X[(size_t)r * HDIM + 4 * q];
            float4 acc = make_float4(0.f, 0.f, 0.f, 0.f);
#pragma unroll
            for (int k = 0; k < HDIM; ++k) {
                float xk = xs[rl][k];
                float4 w4 = *(const float4*)&Ws[k * HDIM + 4 * q];
                acc.x += xk * w4.x; acc.y += xk * w4.y;
                acc.z += xk * w4.z; acc.w += xk * w4.w;
            }
            uint2 pv;
            pv.x = pack_bf16x2(acc.x, acc.y);
            pv.y = pack_bf16x2(acc.z, acc.w);
            *(uint2*)&Yp[(size_t)r * 32 + 2 * q] = pv;
        }
    }
}

// ---------------- fused GCN gather + bias + LN + ReLU ----------------
// half-wave (32 lanes) per node; 4-wide unrolled edge loop for memory parallelism
__global__ void conv_ln(const unsigned* __restrict__ xwp, const int* __restrict__ rp,
                        const int2* __restrict__ csr, const float* __restrict__ dinv,
                        const float* __restrict__ cb, const float* __restrict__ g,
                        const float* __restrict__ b, float* __restrict__ h, int n) {
    int gid = blockIdx.x * blockDim.x + threadIdx.x;
    int node = gid >> 5;
    if (node >= n) return;
    int c2 = gid & 31;
    int wl = threadIdx.x & 63;
    int hb = wl & 32;
    int e0 = rp[node], e1 = rp[node + 1];
    float di = dinv[node];
    float2 self = unpack_bf16x2(xwp[(size_t)node * 32 + c2]);
    float acc0 = self.x * di, acc1 = self.y * di;
    for (int j0 = e0; j0 < e1; j0 += 32) {
        int jj = j0 + c2;
        int sidx = 0; float dv = 0.0f;
        if (jj < e1) { int2 pl = csr[jj]; sidx = pl.x; dv = __int_as_float(pl.y); }
        int cnt = min(32, e1 - j0);
        int k = 0;
        for (; k + 4 <= cnt; k += 4) {
            int sv0 = __shfl(sidx, hb | k);       float f0 = __shfl(dv, hb | k);
            int sv1 = __shfl(sidx, hb | (k + 1)); float f1 = __shfl(dv, hb | (k + 1));
            int sv2 = __shfl(sidx, hb | (k + 2)); float f2 = __shfl(dv, hb | (k + 2));
            int sv3 = __shfl(sidx, hb | (k + 3)); float f3 = __shfl(dv, hb | (k + 3));
            unsigned p0 = xwp[(size_t)sv0 * 32 + c2];
            unsigned p1 = xwp[(size_t)sv1 * 32 + c2];
            unsigned p2 = xwp[(size_t)sv2 * 32 + c2];
            unsigned p3 = xwp[(size_t)sv3 * 32 + c2];
            float2 x0 = unpack_bf16x2(p0), x1 = unpack_bf16x2(p1);
            float2 x2 = unpack_bf16x2(p2), x3 = unpack_bf16x2(p3);
            acc0 += x0.x * f0 + x1.x * f1 + x2.x * f2 + x3.x * f3;
            acc1 += x0.y * f0 + x1.y * f1 + x2.y * f2 + x3.y * f3;
        }
        for (; k < cnt; ++k) {
            int sv = __shfl(sidx, hb | k);
            float fk = __shfl(dv, hb | k);
            float2 xv = unpack_bf16x2(xwp[(size_t)sv * 32 + c2]);
            acc0 += xv.x * fk;
            acc1 += xv.y * fk;
        }
    }
    float2 cbv = *(const float2*)&cb[2 * c2];
    float v0 = acc0 * di + cbv.x;
    float v1 = acc1 * di + cbv.y;
    float s = v0 + v1;
#pragma unroll
    for (int off = 16; off; off >>= 1) s += __shfl_xor(s, off);
    float mu = s * (1.0f / 64.0f);
    float d0 = v0 - mu, d1 = v1 - mu;
    float qq = d0 * d0 + d1 * d1;
#pragma unroll
    for (int off = 16; off; off >>= 1) qq += __shfl_xor(qq, off);
    float r = rsqrtf(qq * (1.0f / 64.0f) + 1e-5f);
    float2 gv = *(const float2*)&g[2 * c2];
    float2 bv = *(const float2*)&b[2 * c2];
    float o0 = fmaxf(d0 * r * gv.x + bv.x, 0.0f);
    float o1 = fmaxf(d1 * r * gv.y + bv.y, 0.0f);
    *(float2*)&h[(size_t)node * HDIM + 2 * c2] = make_float2(o0, o1);
}

// ---------------- residual gather: res[s] = sum adj * xw[dst] ----------------
__global__ void res_gather(const unsigned* __restrict__ xwp, const int* __restrict__ rp,
                           const int2* __restrict__ csr, float* __restrict__ res, int n) {
    int gid = blockIdx.x * blockDim.x + threadIdx.x;
    int node = gid >> 5;
    if (node >= n) return;
    int c2 = gid & 31;
    int wl = threadIdx.x & 63;
    int hb = wl & 32;
    int e0 = rp[node], e1 = rp[node + 1];
    float acc0 = 0.0f, acc1 = 0.0f;
    for (int j0 = e0; j0 < e1; j0 += 32) {
        int jj = j0 + c2;
        int didx = 0; float vv = 0.0f;
        if (jj < e1) { int2 pl = csr[jj]; didx = pl.x; vv = __int_as_float(pl.y); }
        int cnt = min(32, e1 - j0);
        int k = 0;
        for (; k + 4 <= cnt; k += 4) {
            int sv0 = __shfl(didx, hb | k);       float f0 = __shfl(vv, hb | k);
            int sv1 = __shfl(didx, hb | (k + 1)); float f1 = __shfl(vv, hb | (k + 1));
            int sv2 = __shfl(didx, hb | (k + 2)); float f2 = __shfl(vv, hb | (k + 2));
            int sv3 = __shfl(didx, hb | (k + 3)); float f3 = __shfl(vv, hb | (k + 3));
            unsigned p0 = xwp[(size_t)sv0 * 32 + c2];
            unsigned p1 = xwp[(size_t)sv1 * 32 + c2];
            unsigned p2 = xwp[(size_t)sv2 * 32 + c2];
            unsigned p3 = xwp[(size_t)sv3 * 32 + c2];
            float2 x0 = unpack_bf16x2(p0), x1 = unpack_bf16x2(p1);
            float2 x2 = unpack_bf16x2(p2), x3 = unpack_bf16x2(p3);
            acc0 += x0.x * f0 + x1.x * f1 + x2.x * f2 + x3.x * f3;
            acc1 += x0.y * f0 + x1.y * f1 + x2.y * f2 + x3.y * f3;
        }
        for (; k < cnt; ++k) {
            int dv = __shfl(didx, hb | k);
            float fk = __shfl(vv, hb | k);
            float2 xv = unpack_bf16x2(xwp[(size_t)dv * 32 + c2]);
            acc0 += xv.x * fk;
            acc1 += xv.y * fk;
        }
    }
    *(float2*)&res[(size_t)node * HDIM + 2 * c2] = make_float2(acc0, acc1);
}

extern "C" void kernel_launch(void* const* d_in, const int* in_sizes, int n_in,
                              void* d_out, int out_size, void* d_ws, size_t ws_size,
                              hipStream_t stream) {
    const float* x     = (const float*)d_in[0];
    const float* xorg  = (const float*)d_in[1];
    const float* adjv  = (const float*)d_in[2];
    const float* Wi    = (const float*)d_in[3];
    const float* bi    = (const float*)d_in[4];
    const float* convW = (const float*)d_in[5];
    const float* convB = (const float*)d_in[6];
    const float* lng   = (const float*)d_in[7];
    const float* lnb   = (const float*)d_in[8];
    const float* Wl    = (const float*)d_in[9];
    const float* bl    = (const float*)d_in[10];
    const float* Wres  = (const float*)d_in[11];
    const int*   ei    = (const int*)d_in[12];
    const int* src = ei;
    const int* dst = ei + NEDGES;

    float* out = (float*)d_out;               // [N,64]
    float* res = out + (size_t)NNODES * HDIM; // [N,64]

    // ---- workspace layout (round-4) ----
    float* h      = (float*)d_ws;                           // N*64 f32
    unsigned* xwp = (unsigned*)(h + (size_t)NNODES * HDIM); // N*32 u32
    float* dinv   = (float*)(xwp + (size_t)NNODES * 32);    // N
    int* cnt_d    = (int*)(dinv + NNODES);              // N
    int* cnt_s    = cnt_d + NNODES;                     // N
    int* rp_d     = cnt_s + NNODES;                     // N+1
    int* rp_s     = rp_d + (NNODES + 1);                // N+1
    int* cur_d    = rp_s + (NNODES + 1);                // N
    int* cur_s    = cur_d + NNODES;                     // N
    int* bsum_d   = cur_s + NNODES;                     // 256
    int* boff_d   = bsum_d + 256;                       // 256
    int* bsum_s   = boff_d + 256;                       // 256
    int* boff_s   = bsum_s + 256;                       // 256
    size_t ofs = (size_t)(boff_s + 256 - (int*)d_ws);
    ofs = (ofs + 1) & ~(size_t)1;
    int2* csr_d = (int2*)((int*)d_ws + ofs);            // E int2
    int2* csr_s = csr_d + NEDGES;                       // E int2

    const int ngrid1 = (NNODES + 255) / 256;
    const int ngrid32 = (NNODES * 32 + 255) / 256;

    // ---- CSR build ----
    hipMemsetAsync(cnt_d, 0, 2 * (size_t)NNODES * sizeof(int), stream);
    hist4<<<(NEDGES / 4 + 255) / 256, 256, 0, stream>>>(
        (const int4*)src, (const int4*)dst, cnt_s, cnt_d, NEDGES / 4);
    make_dinv<<<ngrid1, 256, 0, stream>>>(cnt_d, dinv, NNODES);

    scan1<<<NBLK_SCAN, SCAN_BS, 0, stream>>>(cnt_d, rp_d, bsum_d, NNODES);
    scan1<<<NBLK_SCAN, SCAN_BS, 0, stream>>>(cnt_s, rp_s, bsum_s, NNODES);
    scan2<<<1, 256, 0, stream>>>(bsum_d, boff_d, NBLK_SCAN);
    scan2<<<1, 256, 0, stream>>>(bsum_s, boff_s, NBLK_SCAN);
    scan3<<<ngrid1, 256, 0, stream>>>(rp_d, cur_d, boff_d, NNODES, NEDGES);
    scan3<<<ngrid1, 256, 0, stream>>>(rp_s, cur_s, boff_s, NNODES, NEDGES);
    fill_csr_part<<<2048, 256, 0, stream>>>(src, dst, adjv, dinv, cur_d, cur_s,
                                            csr_d, csr_s, NEDGES);

    // ---- h0 = relu(x @ Wi + bi) ----
    gemm64<<<2048, 256, 0, stream>>>(x, Wi, bi, h, NNODES, 1);

    // ---- residual = gather_src(adj * (x_org @ Wres)[dst]) ----
    gemm64p<<<2048, 256, 0, stream>>>(xorg, Wres, xwp, NNODES);
    res_gather<<<ngrid32, 256, 0, stream>>>(xwp, rp_s, csr_s, res, NNODES);

    // ---- 3 GCN layers: packed gemm -> fused gather+LN+ReLU ----
    for (int l = 0; l < 3; ++l) {
        gemm64p<<<2048, 256, 0, stream>>>(h, convW + l * HDIM * HDIM, xwp, NNODES);
        conv_ln<<<ngrid32, 256, 0, stream>>>(xwp, rp_d, csr_d, dinv,
                                             convB + l * HDIM, lng + l * HDIM,
                                             lnb + l * HDIM, h, NNODES);
    }

    // ---- out = h @ Wl + bl ----
    gemm64<<<2048, 256, 0, stream>>>(h, Wl, bl, out, NNODES, 0);
}